// Round 16
// baseline (744.664 us; speedup 1.0000x reference)
//
#include <hip/hip_runtime.h>
#include <hip/hip_bf16.h>

typedef __hip_bfloat16 bf16;

#define CUT 14
#define D2 196
#define D3 2744

#define SX 0
#define STH1 1
#define SPH1 2
#define SVPH1 3
#define SR 4
#define SPHR 5
#define STH2 6
#define SPH2 7
#define SVPH2 8
#define SA 9
#define SPHA 10
#define SK 11

// c_SOFF[n] = sum_{n'<n} s(n'), s(n)=min(13,n)-max(0,n-13)+1 (sorted-pos offsets)
__constant__ int c_SOFF[27] = {0,1,3,6,10,15,21,28,36,45,55,66,78,91,
                               105,118,130,141,151,160,168,175,181,186,190,193,195};

struct P12 { const void* p[12]; };

// BS gates: [gate][ci 0..13][spos 0..195], zero-padded for ci >= s(n).
__device__ float2 g_gpad[24 * D3];
__device__ float2 g_gsr[12 * D2];
__device__ float2 g_grdk[12 * D2];
// element map for k-major BS apply: 2744 x packed (n | a<<8 | k<<16 | spos<<24),
// elements sorted by block size s (descending) so passes have uniform trip count
__device__ unsigned int g_emap[D3];
__device__ int g_flag;
__device__ int g_map[12];

__device__ __forceinline__ float2 cfma2(float2 acc, float2 a, float2 b) {
    acc.x = fmaf(a.x, b.x, fmaf(-a.y, b.y, acc.x));
    acc.y = fmaf(a.x, b.y, fmaf(a.y, b.x, acc.y));
    return acc;
}
__device__ __forceinline__ float2 cmul2(float2 a, float2 b) {
    return make_float2(a.x*b.x - a.y*b.y, a.x*b.y + a.y*b.x);
}
__device__ __forceinline__ float load_raw(const void* p, int i, int f32) {
    return f32 ? ((const float*)p)[i]
               : __bfloat162float(((const bf16*)p)[i]);
}

// Per-block layout/dtype detection (R5-proven: dict order, fp32, r/a at {4,9}).
__device__ void detect_layout(const P12& P, int ix, int* sh)
{
    int t = threadIdx.x;
    if (t < 13) sh[13 + t] = 0;
    __syncthreads();
    const unsigned int* u = (const unsigned int*)P.p[ix];
    if (t < 256) {
        if (u[t] & 0x8000u) atomicOr(&sh[25], 1);
    }
    __syncthreads();
    int f = sh[25] != 0 ? 1 : 0;
    if (t < 144) {
        int p = t / 12, j = t - (t/12)*12;
        if (p != ix) {
            float v = fabsf(load_raw(P.p[p], j, f));
            atomicMax(&sh[13 + p], __float_as_int(v));
        }
    }
    __syncthreads();
    if (t == 0) {
        int mask = 0;
        for (int i = 0; i < 12; ++i) {
            if (i == ix) continue;
            if (__int_as_float(sh[13 + i]) < 0.2f) mask |= (1 << i);
        }
        const int dict_map[12]  = {0,1,2,3,4,5,6,7,8,9,10,11};
        const int alpha_map[12] = {11,7,2,9,6,5,8,3,10,0,4,1};
        const int* m = (ix == 11 && mask == ((1<<0)|(1<<6))) ? alpha_map : dict_map;
        for (int i = 0; i < 12; ++i) sh[i] = m[i];
        sh[12] = f;
    }
    __syncthreads();
}

// expm light: scale 2^-10, 10 Taylor terms, 10 squarings (R15-proven accurate).
__device__ void expm_lds(float2* B, float2* TERM, float2* OUT, float2* TMP, int s, int t)
{
    const int s2 = s * s;
    if (t < s2) { B[t].x *= (1.0f/1024.0f); B[t].y *= (1.0f/1024.0f); }
    __syncthreads();
    if (t < s2) {
        float2 id = make_float2((t % (s + 1) == 0) ? 1.0f : 0.0f, 0.0f);
        TERM[t] = id; OUT[t] = id;
    }
    __syncthreads();
    for (int kk = 1; kk <= 10; ++kk) {
        if (t < s2) {
            int i = t / s, j = t - i * s;
            float2 acc = make_float2(0.f, 0.f);
            for (int k = 0; k < s; ++k) acc = cfma2(acc, TERM[i*s+k], B[k*s+j]);
            float inv = 1.0f / (float)kk;
            TMP[t] = make_float2(acc.x*inv, acc.y*inv);
        }
        __syncthreads();
        if (t < s2) { TERM[t] = TMP[t]; OUT[t].x += TMP[t].x; OUT[t].y += TMP[t].y; }
        __syncthreads();
    }
    for (int q = 0; q < 10; ++q) {
        if (t < s2) {
            int i = t / s, j = t - i * s;
            float2 acc = make_float2(0.f, 0.f);
            for (int k = 0; k < s; ++k) acc = cfma2(acc, OUT[i*s+k], OUT[k*s+j]);
            TMP[t] = acc;
        }
        __syncthreads();
        if (t < s2) OUT[t] = TMP[t];
        __syncthreads();
    }
}

// Unified builder: 0..647 BS gates, 648..671 singles, 672 element map.
__global__ __launch_bounds__(256)
void build_all(P12 P, int ix)
{
    __shared__ float2 B[D2], TERM[D2], OUT[D2], TMP[D2];
    __shared__ int sh[26];
    int t = threadIdx.x;
    detect_layout(P, ix, sh);
    const int f32 = sh[12];
    if (blockIdx.x == 0 && t == 0) {
        for (int i = 0; i < 12; ++i) g_map[i] = sh[i];
        g_flag = f32;
    }
    #define LS(slot, i) load_raw(P.p[sh[(slot)]], (i), f32)

    if (blockIdx.x < 648) {
        int gate = blockIdx.x / 27;
        int n    = blockIdx.x % 27;
        int cc   = gate / 12;
        int l    = (gate / 6) % 2;
        int slot = gate % 6;
        int p    = slot % 3;
        int pidx = (cc*2 + l)*3 + p;
        float th = LS(slot < 3 ? STH1 : STH2, pidx);
        float ph = LS(slot < 3 ? SPH1 : SPH2, pidx);
        float cph, sph; sincosf(ph, &sph, &cph);
        int cmin = max(0, n - 13);
        int cmax = min(13, n);
        int s = cmax - cmin + 1;
        if (t < s*s) {
            int i = t / s, j = t - (t/s)*s;
            float2 h = make_float2(0.f, 0.f);
            int cj = cmin + j;
            if (i == j + 1) {
                float sq = th * sqrtf((float)((cj+1)*(n-cj)));
                h = make_float2(sq*cph, sq*sph);
            } else if (i == j - 1) {
                float sq = th * sqrtf((float)(cj*(n-cj+1)));
                h = make_float2(-sq*cph, sq*sph);
            }
            B[t] = h;
        }
        __syncthreads();
        expm_lds(B, TERM, OUT, TMP, s, t);
        if (t < s*14) {
            int ii = t / 14, ci = t - (t/14)*14;
            float2 v = (ci < s) ? OUT[ii*s + ci] : make_float2(0.f, 0.f);
            g_gpad[gate*D3 + ci*196 + (c_SOFF[n] + ii)] = v;
        }
    } else if (blockIdx.x < 672) {
        int q = blockIdx.x - 648;        // 0..23
        int pidx = q >> 1;
        if ((q & 1) == 0) {
            // gsr = SQ(r,phi_r) @ diag(e^{i varphi1 j})
            float rv = LS(SR, pidx);
            float pv = LS(SPHR, pidx);
            float cp, sp; sincosf(pv, &sp, &cp);
            if (t < D2) {
                int i = t / 14, j = t - (t/14)*14;
                float2 h = make_float2(0.f, 0.f);
                if (j == i + 2) {
                    float s = 0.5f * rv * sqrtf((float)((i+1)*(i+2)));
                    h = make_float2(s*cp, -s*sp);
                } else if (i == j + 2) {
                    float s = 0.5f * rv * sqrtf((float)((j+1)*(j+2)));
                    h = make_float2(-s*cp, -s*sp);
                }
                B[t] = h;
            }
            __syncthreads();
            expm_lds(B, TERM, OUT, TMP, 14, t);
            float v1 = LS(SVPH1, pidx);
            if (t < D2) {
                int j = t - (t/14)*14;
                float cs, sn; sincosf(v1 * (float)j, &sn, &cs);
                g_gsr[pidx*D2 + t] = cmul2(OUT[t], make_float2(cs, sn));
            }
        } else {
            // grdk = diag(e^{i k i^2}) @ D(a,phi_a) @ diag(e^{i varphi2 j})
            float av = LS(SA, pidx);
            float pav = LS(SPHA, pidx);
            float ca, sa; sincosf(pav, &sa, &ca);
            if (t < D2) {
                int i = t / 14, j = t - (t/14)*14;
                float2 h = make_float2(0.f, 0.f);
                if (i == j + 1) {
                    float s = av * sqrtf((float)(j+1));
                    h = make_float2(s*ca, s*sa);
                } else if (j == i + 1) {
                    float s = av * sqrtf((float)(i+1));
                    h = make_float2(-s*ca, s*sa);
                }
                B[t] = h;
            }
            __syncthreads();
            expm_lds(B, TERM, OUT, TMP, 14, t);
            float v2 = LS(SVPH2, pidx);
            float kv = LS(SK, pidx);
            if (t < D2) {
                int i = t / 14, j = t - (t/14)*14;
                float ang = kv * (float)(i*i) + v2 * (float)j;
                float cs, sn; sincosf(ang, &sn, &cs);
                g_grdk[pidx*D2 + t] = cmul2(OUT[t], make_float2(cs, sn));
            }
        }
    } else {
        // element map: blocks ordered by s desc: q=0 -> n=13; odd q -> 13-(q+1)/2;
        // even q -> 13+q/2. Within block: k outer (0..13), a inner (cmin..cmax).
        for (int e = t; e < D3; e += 256) {
            int cum = 0, n = 13, s = 14, off = 0;
            for (int q = 0; q < 27; ++q) {
                int nn = (q == 0) ? 13 : ((q & 1) ? 13 - (q+1)/2 : 13 + q/2);
                int cmn = max(0, nn-13), cmx = min(13, nn);
                int ss = cmx - cmn + 1;
                int sz = 14 * ss;
                if (e >= cum && e < cum + sz) { n = nn; s = ss; off = e - cum; }
                cum += sz;
            }
            int cmin = max(0, n-13);
            int k = off / s;
            int a = cmin + (off - k*s);
            int spos = c_SOFF[n] + (a - cmin);
            g_emap[e] = (unsigned)n | ((unsigned)a << 8) |
                        ((unsigned)k << 16) | ((unsigned)spos << 24);
        }
    }
    #undef LS
}

// ---- k-major BS apply: lane = output element (n,a,k); 11 passes; in-place
// (all reads -> barrier -> all writes, acc held in registers). Reads within an
// (n,k) run hit the SAME ps address -> LDS broadcast (free). ----
template<int PAIR>
__device__ __attribute__((noinline))
void apply_bs(const float2* __restrict__ G, float2* ps, int t)
{
    float2 acc[11];
    unsigned int mp[11];
    #pragma unroll
    for (int p = 0; p < 11; ++p) {
        int e = p*256 + t;
        mp[p] = (e < D3) ? g_emap[e] : 0xFFFFFFFFu;
    }
    #pragma unroll
    for (int p = 0; p < 11; ++p) {
        acc[p] = make_float2(0.f, 0.f);
        unsigned int m = mp[p];
        if (m != 0xFFFFFFFFu) {
            int n    = m & 0xFF;
            int k    = (m >> 16) & 0xFF;
            int spos = (m >> 24) & 0xFF;
            int cmin = max(0, n-13);
            int s = min(13, n) - cmin + 1;
            const float2* gp = G + spos;
            int src = (PAIR == 0) ? (cmin*14 + (n-cmin))*14 + k
                                  : k*196 + cmin*14 + (n-cmin);
            const int dsrc = (PAIR == 0) ? 182 : 13;
            for (int ci = 0; ci < s; ++ci) {
                acc[p] = cfma2(acc[p], gp[ci*196], ps[src]);
                src += dsrc;
            }
        }
    }
    __syncthreads();
    #pragma unroll
    for (int p = 0; p < 11; ++p) {
        unsigned int m = mp[p];
        if (m != 0xFFFFFFFFu) {
            int n = m & 0xFF;
            int a = (m >> 8) & 0xFF;
            int k = (m >> 16) & 0xFF;
            int dst = (PAIR == 0) ? (a*14 + (n-a))*14 + k
                                  : k*196 + a*14 + (n-a);
            ps[dst] = acc[p];
        }
    }
    __syncthreads();
}

// Singles: thread owns its fiber exclusively -> in-place, register reuse.
template<int MODE>
__device__ void apply_single(const float2* __restrict__ U, float2* ps, int t)
{
    if (t < D2) {
        int base, stride;
        if (MODE == 0)      { base = t; stride = 196; }
        else if (MODE == 1) { base = (t/14)*196 + (t % 14); stride = 14; }
        else                { base = t*14; stride = 1; }
        float2 fib[14];
        #pragma unroll
        for (int j = 0; j < 14; ++j) fib[j] = ps[base + j*stride];
        #pragma unroll
        for (int i = 0; i < 14; ++i) {
            float2 acc = make_float2(0.f, 0.f);
            #pragma unroll
            for (int j = 0; j < 14; ++j) acc = cfma2(acc, U[i*14 + j], fib[j]);
            ps[base + i*stride] = acc;
        }
    }
    __syncthreads();
}

__global__ __launch_bounds__(256)
void qcircuit(P12 P, float* __restrict__ out)
{
    __shared__ float2 ps[D3];
    __shared__ float cohr[3][14];
    __shared__ float red[12];
    int t = threadIdx.x;
    int b = blockIdx.x >> 1;
    int c = blockIdx.x & 1;
    int base6 = b*6 + c*3;
    int f32 = g_flag;

    if (t < 42) {
        int m = t / 14, n = t - (t/14)*14;
        float xv = load_raw(P.p[g_map[SX]], base6 + m, f32);
        float p = 1.0f;
        for (int q = 0; q < n; ++q) p *= xv;
        float f = 1.0f;
        for (int q = 2; q <= n; ++q) f *= (float)q;
        cohr[m][n] = expf(-0.5f*xv*xv) * p / sqrtf(f);
    }
    __syncthreads();
    for (int idx = t; idx < D3; idx += 256) {
        int i2 = idx % 14, i1 = (idx/14) % 14, i0 = idx / 196;
        ps[idx] = make_float2(cohr[0][i0]*cohr[1][i1]*cohr[2][i2], 0.f);
    }
    __syncthreads();

    for (int l = 0; l < 2; ++l) {
        int gi = c*2 + l;
        const float2* bsb = g_gpad + gi*6*D3;
        apply_bs<0>(bsb + 0*D3, ps, t);
        apply_bs<1>(bsb + 1*D3, ps, t);
        apply_bs<0>(bsb + 2*D3, ps, t);
        apply_single<0>(g_gsr + (gi*3+0)*D2, ps, t);
        apply_single<1>(g_gsr + (gi*3+1)*D2, ps, t);
        apply_single<2>(g_gsr + (gi*3+2)*D2, ps, t);
        apply_bs<0>(bsb + 3*D3, ps, t);
        apply_bs<1>(bsb + 4*D3, ps, t);
        apply_bs<0>(bsb + 5*D3, ps, t);
        apply_single<0>(g_grdk + (gi*3+0)*D2, ps, t);
        apply_single<1>(g_grdk + (gi*3+1)*D2, ps, t);
        apply_single<2>(g_grdk + (gi*3+2)*D2, ps, t);
    }

    // <X_m> = 2 * sum sqrt(i_m+1) Re(conj(psi_i) psi_{i+e_m})
    float p0 = 0.f, p1 = 0.f, p2 = 0.f;
    for (int idx = t; idx < D3; idx += 256) {
        int i2 = idx % 14, i1 = (idx/14) % 14, i0 = idx / 196;
        float2 v = ps[idx];
        if (i0 < 13) { float2 w = ps[idx + 196]; p0 += sqrtf((float)(i0+1)) * (v.x*w.x + v.y*w.y); }
        if (i1 < 13) { float2 w = ps[idx + 14];  p1 += sqrtf((float)(i1+1)) * (v.x*w.x + v.y*w.y); }
        if (i2 < 13) { float2 w = ps[idx + 1];   p2 += sqrtf((float)(i2+1)) * (v.x*w.x + v.y*w.y); }
    }
    #pragma unroll
    for (int off = 32; off > 0; off >>= 1) {
        p0 += __shfl_down(p0, off, 64);
        p1 += __shfl_down(p1, off, 64);
        p2 += __shfl_down(p2, off, 64);
    }
    int lane = t & 63, w = t >> 6;
    if (lane == 0) { red[w*3+0] = p0; red[w*3+1] = p1; red[w*3+2] = p2; }
    __syncthreads();
    if (t == 0) {
        float o0 = 0.f, o1 = 0.f, o2 = 0.f;
        for (int q = 0; q < 4; ++q) { o0 += red[q*3]; o1 += red[q*3+1]; o2 += red[q*3+2]; }
        out[base6 + 0] = 2.0f * o0;
        out[base6 + 1] = 2.0f * o1;
        out[base6 + 2] = 2.0f * o2;
    }
}

extern "C" void kernel_launch(void* const* d_in, const int* in_sizes, int n_in,
                              void* d_out, int out_size, void* d_ws, size_t ws_size,
                              hipStream_t stream) {
    (void)d_ws; (void)ws_size;
    P12 P;
    for (int i = 0; i < 12; ++i) P.p[i] = (i < n_in) ? d_in[i] : nullptr;
    float* out = (float*)d_out;

    int ix = 0; long best = -1;
    for (int i = 0; i < 12 && i < n_in; ++i)
        if ((long)in_sizes[i] > best) { best = in_sizes[i]; ix = i; }
    int B = out_size / 6; if (B < 1) B = 1;

    build_all<<<673, 256, 0, stream>>>(P, ix);
    qcircuit<<<2*B, 256, 0, stream>>>(P, out);
}

// Round 17
// 487.488 us; speedup vs baseline: 1.5276x; 1.5276x over previous
//
#include <hip/hip_runtime.h>
#include <hip/hip_bf16.h>

typedef __hip_bfloat16 bf16;

#define CUT 14
#define D2 196
#define D3 2744
#define GSTRIDE 3584   // 14 ci * 256 threads per gate slab

#define SX 0
#define STH1 1
#define SPH1 2
#define SVPH1 3
#define SR 4
#define SPHR 5
#define STH2 6
#define SPH2 7
#define SVPH2 8
#define SA 9
#define SPHA 10
#define SK 11

// Packed thread->(n,a) map: every photon-number block fits inside ONE wave,
// so BS applies are wave-internal (no write barrier needed). [R15-proven]
__constant__ unsigned char c_PN[256] = {
13,13,13,13,13,13,13,13,13,13,13,13,13,13,
12,12,12,12,12,12,12,12,12,12,12,12,12,
14,14,14,14,14,14,14,14,14,14,14,14,14,
11,11,11,11,11,11,11,11,11,11,11,11,
15,15,15,15,15,15,15,15,15,15,15,15,
10,10,10,10,10,10,10,10,10,10,10,
16,16,16,16,16,16,16,16,16,16,16,
9,9,9,9,9,9,9,9,9,9,
17,17,17,17,17,17,17,17,17,17,
8,8,8,8,8,8,8,8,8,
18,18,18,18,18,18,18,18,18,
3,3,3,3,
7,7,7,7,7,7,7,7,
19,19,19,19,19,19,19,19,
6,6,6,6,6,6,6,
20,20,20,20,20,20,20,
5,5,5,5,5,5,
21,21,21,21,21,21,
4,4,4,4,4,
22,22,22,22,22,
23,23,23,23,
2,2,2,
24,24,24,
1,1,
25,25,
0,
26,
255,255,255,255,255,255,255,255,255,255,255,255,255,255,255,
255,255,255,255,255,255,255,255,255,255,255,255,255,255,255,
255,255,255,255,255,255,255,255,255,255,255,255,255,255,255,
255,255,255,255,255,255,255,255,255,255,255,255,255,255,255};
__constant__ unsigned char c_PA[256] = {
0,1,2,3,4,5,6,7,8,9,10,11,12,13,
0,1,2,3,4,5,6,7,8,9,10,11,12,
1,2,3,4,5,6,7,8,9,10,11,12,13,
0,1,2,3,4,5,6,7,8,9,10,11,
2,3,4,5,6,7,8,9,10,11,12,13,
0,1,2,3,4,5,6,7,8,9,10,
3,4,5,6,7,8,9,10,11,12,13,
0,1,2,3,4,5,6,7,8,9,
4,5,6,7,8,9,10,11,12,13,
0,1,2,3,4,5,6,7,8,
5,6,7,8,9,10,11,12,13,
0,1,2,3,
0,1,2,3,4,5,6,7,
6,7,8,9,10,11,12,13,
0,1,2,3,4,5,6,
7,8,9,10,11,12,13,
0,1,2,3,4,5,
8,9,10,11,12,13,
0,1,2,3,4,
9,10,11,12,13,
10,11,12,13,
0,1,2,
11,12,13,
0,1,
12,13,
0,
13,
0,0,0,0,0,0,0,0,0,0,0,0,0,0,0,
0,0,0,0,0,0,0,0,0,0,0,0,0,0,0,
0,0,0,0,0,0,0,0,0,0,0,0,0,0,0,
0,0,0,0,0,0,0,0,0,0,0,0,0,0,0};
// n -> packed start thread index
__constant__ short c_PSTART[27] = {194,190,184,124,170,158,144,128,106,86,64,40,14,0,
                                   27,52,75,96,115,136,151,164,175,180,187,192,195};

struct P12 { const void* p[12]; };

__device__ float2 g_gp[24 * GSTRIDE];   // BS gates, packed layout [gate][ci][t]
__device__ float2 g_gsr[12 * D2];
__device__ float2 g_grdk[12 * D2];
__device__ int    g_flag;
__device__ int    g_map[12];

__device__ __forceinline__ float2 cfma2(float2 acc, float2 a, float2 b) {
    acc.x = fmaf(a.x, b.x, fmaf(-a.y, b.y, acc.x));
    acc.y = fmaf(a.x, b.y, fmaf(a.y, b.x, acc.y));
    return acc;
}
__device__ __forceinline__ float2 cmul2(float2 a, float2 b) {
    return make_float2(a.x*b.x - a.y*b.y, a.x*b.y + a.y*b.x);
}
__device__ __forceinline__ float load_raw(const void* p, int i, int f32) {
    return f32 ? ((const float*)p)[i]
               : __bfloat162float(((const bf16*)p)[i]);
}

// Per-block layout/dtype detection (R5-proven: dict order, fp32, r/a at {4,9}).
__device__ void detect_layout(const P12& P, int ix, int* sh)
{
    int t = threadIdx.x;
    if (t < 13) sh[13 + t] = 0;
    __syncthreads();
    const unsigned int* u = (const unsigned int*)P.p[ix];
    if (t < 256) {
        if (u[t] & 0x8000u) atomicOr(&sh[25], 1);
    }
    __syncthreads();
    int f = sh[25] != 0 ? 1 : 0;
    if (t < 144) {
        int p = t / 12, j = t - (t/12)*12;
        if (p != ix) {
            float v = fabsf(load_raw(P.p[p], j, f));
            atomicMax(&sh[13 + p], __float_as_int(v));
        }
    }
    __syncthreads();
    if (t == 0) {
        int mask = 0;
        for (int i = 0; i < 12; ++i) {
            if (i == ix) continue;
            if (__int_as_float(sh[13 + i]) < 0.2f) mask |= (1 << i);
        }
        const int dict_map[12]  = {0,1,2,3,4,5,6,7,8,9,10,11};
        const int alpha_map[12] = {11,7,2,9,6,5,8,3,10,0,4,1};
        const int* m = (ix == 11 && mask == ((1<<0)|(1<<6))) ? alpha_map : dict_map;
        for (int i = 0; i < 12; ++i) sh[i] = m[i];
        sh[12] = f;
    }
    __syncthreads();
}

// expm light: scale 2^-10, 10 Taylor terms, 10 squarings (R15-proven accurate).
__device__ void expm_lds(float2* B, float2* TERM, float2* OUT, float2* TMP, int s, int t)
{
    const int s2 = s * s;
    if (t < s2) { B[t].x *= (1.0f/1024.0f); B[t].y *= (1.0f/1024.0f); }
    __syncthreads();
    if (t < s2) {
        float2 id = make_float2((t % (s + 1) == 0) ? 1.0f : 0.0f, 0.0f);
        TERM[t] = id; OUT[t] = id;
    }
    __syncthreads();
    for (int kk = 1; kk <= 10; ++kk) {
        if (t < s2) {
            int i = t / s, j = t - i * s;
            float2 acc = make_float2(0.f, 0.f);
            for (int k = 0; k < s; ++k) acc = cfma2(acc, TERM[i*s+k], B[k*s+j]);
            float inv = 1.0f / (float)kk;
            TMP[t] = make_float2(acc.x*inv, acc.y*inv);
        }
        __syncthreads();
        if (t < s2) { TERM[t] = TMP[t]; OUT[t].x += TMP[t].x; OUT[t].y += TMP[t].y; }
        __syncthreads();
    }
    for (int q = 0; q < 10; ++q) {
        if (t < s2) {
            int i = t / s, j = t - i * s;
            float2 acc = make_float2(0.f, 0.f);
            for (int k = 0; k < s; ++k) acc = cfma2(acc, OUT[i*s+k], OUT[k*s+j]);
            TMP[t] = acc;
        }
        __syncthreads();
        if (t < s2) OUT[t] = TMP[t];
        __syncthreads();
    }
}

// Unified builder: blocks 0..647 = BS gates (gate,n); 648..671 = singles.
__global__ __launch_bounds__(256)
void build_all(P12 P, int ix)
{
    __shared__ float2 B[D2], TERM[D2], OUT[D2], TMP[D2];
    __shared__ int sh[26];
    int t = threadIdx.x;
    detect_layout(P, ix, sh);
    const int f32 = sh[12];
    if (blockIdx.x == 0 && t == 0) {
        for (int i = 0; i < 12; ++i) g_map[i] = sh[i];
        g_flag = f32;
    }
    #define LS(slot, i) load_raw(P.p[sh[(slot)]], (i), f32)

    if (blockIdx.x < 648) {
        int gate = blockIdx.x / 27;
        int n    = blockIdx.x % 27;
        int cc   = gate / 12;
        int l    = (gate / 6) % 2;
        int slot = gate % 6;
        int p    = slot % 3;
        int pidx = (cc*2 + l)*3 + p;
        float th = LS(slot < 3 ? STH1 : STH2, pidx);
        float ph = LS(slot < 3 ? SPH1 : SPH2, pidx);
        float cph, sph; sincosf(ph, &sph, &cph);
        int cmin = max(0, n - 13);
        int cmax = min(13, n);
        int s = cmax - cmin + 1;
        if (t < s*s) {
            int i = t / s, j = t - (t/s)*s;
            float2 h = make_float2(0.f, 0.f);
            int cj = cmin + j;
            if (i == j + 1) {
                float sq = th * sqrtf((float)((cj+1)*(n-cj)));
                h = make_float2(sq*cph, sq*sph);
            } else if (i == j - 1) {
                float sq = th * sqrtf((float)(cj*(n-cj+1)));
                h = make_float2(-sq*cph, sq*sph);
            }
            B[t] = h;
        }
        __syncthreads();
        expm_lds(B, TERM, OUT, TMP, s, t);
        if (t < s*14) {
            int ii = t / 14, ci = t - (t/14)*14;
            float2 v = (ci < s) ? OUT[ii*s + ci] : make_float2(0.f, 0.f);
            g_gp[gate*GSTRIDE + ci*256 + (c_PSTART[n] + ii)] = v;
        }
    } else {
        int q = blockIdx.x - 648;        // 0..23
        int pidx = q >> 1;
        if ((q & 1) == 0) {
            // gsr = SQ(r,phi_r) @ diag(e^{i varphi1 j})
            float rv = LS(SR, pidx);
            float pv = LS(SPHR, pidx);
            float cp, sp; sincosf(pv, &sp, &cp);
            if (t < D2) {
                int i = t / 14, j = t - (t/14)*14;
                float2 h = make_float2(0.f, 0.f);
                if (j == i + 2) {
                    float s = 0.5f * rv * sqrtf((float)((i+1)*(i+2)));
                    h = make_float2(s*cp, -s*sp);
                } else if (i == j + 2) {
                    float s = 0.5f * rv * sqrtf((float)((j+1)*(j+2)));
                    h = make_float2(-s*cp, -s*sp);
                }
                B[t] = h;
            }
            __syncthreads();
            expm_lds(B, TERM, OUT, TMP, 14, t);
            float v1 = LS(SVPH1, pidx);
            if (t < D2) {
                int j = t - (t/14)*14;
                float cs, sn; sincosf(v1 * (float)j, &sn, &cs);
                g_gsr[pidx*D2 + t] = cmul2(OUT[t], make_float2(cs, sn));
            }
        } else {
            // grdk = diag(e^{i k i^2}) @ D(a,phi_a) @ diag(e^{i varphi2 j})
            float av = LS(SA, pidx);
            float pav = LS(SPHA, pidx);
            float ca, sa; sincosf(pav, &sa, &ca);
            if (t < D2) {
                int i = t / 14, j = t - (t/14)*14;
                float2 h = make_float2(0.f, 0.f);
                if (i == j + 1) {
                    float s = av * sqrtf((float)(j+1));
                    h = make_float2(s*ca, s*sa);
                } else if (j == i + 1) {
                    float s = av * sqrtf((float)(i+1));
                    h = make_float2(-s*ca, s*sa);
                }
                B[t] = h;
            }
            __syncthreads();
            expm_lds(B, TERM, OUT, TMP, 14, t);
            float v2 = LS(SVPH2, pidx);
            float kv = LS(SK, pidx);
            if (t < D2) {
                int i = t / 14, j = t - (t/14)*14;
                float ang = kv * (float)(i*i) + v2 * (float)j;
                float cs, sn; sincosf(ang, &sn, &cs);
                g_grdk[pidx*D2 + t] = cmul2(OUT[t], make_float2(cs, sn));
            }
        }
    }
    #undef LS
}

// ---- main circuit kernel: single psi buffer; BS applies wave-internal ----
// PAIR=0: spectator i2 is contiguous -> b128 (float4) reads/writes, halving
// the LDS issue count (the measured bottleneck). PAIR=1: scalar b64 path.

template<int PAIR>
__device__ void apply_bs(const float2* __restrict__ G, float2* ps, int t,
                         int aP, int nP, int sP, int cminP)
{
    if (nP != 255) {
        float2 u[14];
        #pragma unroll
        for (int ci = 0; ci < 14; ++ci) u[ci] = G[ci*256 + t];
        float2 acc[14];
        #pragma unroll
        for (int k = 0; k < 14; ++k) acc[k] = make_float2(0.f, 0.f);
        if (PAIR == 0) {
            const float4* ps4 = (const float4*)ps;
            #pragma unroll
            for (int ci = 0; ci < 14; ++ci) {
                if (ci < sP) {
                    int c = cminP + ci;
                    const float4* sp4 = ps4 + (c*14 + (nP - c))*7;
                    #pragma unroll
                    for (int q = 0; q < 7; ++q) {
                        float4 r = sp4[q];
                        acc[2*q]   = cfma2(acc[2*q],   u[ci], make_float2(r.x, r.y));
                        acc[2*q+1] = cfma2(acc[2*q+1], u[ci], make_float2(r.z, r.w));
                    }
                }
            }
            // wave-internal: writes ordered after reads within this wave
            float4* dp4 = (float4*)ps + (aP*14 + (nP - aP))*7;
            #pragma unroll
            for (int q = 0; q < 7; ++q)
                dp4[q] = make_float4(acc[2*q].x, acc[2*q].y, acc[2*q+1].x, acc[2*q+1].y);
        } else {
            #pragma unroll
            for (int ci = 0; ci < 14; ++ci) {
                if (ci < sP) {
                    int c = cminP + ci;
                    const float2* sp = ps + c*14 + (nP - c);
                    #pragma unroll
                    for (int k = 0; k < 14; ++k)
                        acc[k] = cfma2(acc[k], u[ci], sp[k*196]);
                }
            }
            float2* dp = ps + aP*14 + (nP - aP);
            #pragma unroll
            for (int k = 0; k < 14; ++k) dp[k*196] = acc[k];
        }
    }
    __syncthreads();
}

// Singles: thread owns its fiber exclusively -> in-place. MODE 2 is contiguous
// -> b128 vectorized.
template<int MODE>
__device__ void apply_single(const float2* __restrict__ U, float2* ps, int t)
{
    if (t < D2) {
        float2 fib[14];
        if (MODE == 2) {
            const float4* bp = (const float4*)ps + t*7;
            #pragma unroll
            for (int q = 0; q < 7; ++q) {
                float4 r = bp[q];
                fib[2*q]   = make_float2(r.x, r.y);
                fib[2*q+1] = make_float2(r.z, r.w);
            }
            float2 res[14];
            #pragma unroll
            for (int i = 0; i < 14; ++i) {
                float2 acc = make_float2(0.f, 0.f);
                #pragma unroll
                for (int j = 0; j < 14; ++j) acc = cfma2(acc, U[i*14 + j], fib[j]);
                res[i] = acc;
            }
            float4* dp = (float4*)ps + t*7;
            #pragma unroll
            for (int q = 0; q < 7; ++q)
                dp[q] = make_float4(res[2*q].x, res[2*q].y, res[2*q+1].x, res[2*q+1].y);
        } else {
            int base, stride;
            if (MODE == 0) { base = t; stride = 196; }
            else           { base = (t/14)*196 + (t % 14); stride = 14; }
            #pragma unroll
            for (int j = 0; j < 14; ++j) fib[j] = ps[base + j*stride];
            #pragma unroll
            for (int i = 0; i < 14; ++i) {
                float2 acc = make_float2(0.f, 0.f);
                #pragma unroll
                for (int j = 0; j < 14; ++j) acc = cfma2(acc, U[i*14 + j], fib[j]);
                ps[base + i*stride] = acc;
            }
        }
    }
    __syncthreads();
}

#define ABS0(G) apply_bs<0>(G, ps, t, aP, nP, sP, cminP);
#define ABS1(G) apply_bs<1>(G, ps, t, aP, nP, sP, cminP);

__global__ __launch_bounds__(256, 7)
void qcircuit(P12 P, float* __restrict__ out)
{
    __shared__ __align__(16) float2 ps[D3];
    __shared__ float cohr[3][14];
    __shared__ float red[12];
    int t = threadIdx.x;
    int b = blockIdx.x >> 1;
    int c = blockIdx.x & 1;
    int base6 = b*6 + c*3;
    int f32 = g_flag;

    int nP = (int)c_PN[t];
    int aP = (int)c_PA[t];
    int cminP = max(0, nP - 13);
    int sP = min(13, nP) - cminP + 1;

    if (t < 42) {
        int m = t / 14, n = t - (t/14)*14;
        float xv = load_raw(P.p[g_map[SX]], base6 + m, f32);
        float p = 1.0f;
        for (int q = 0; q < n; ++q) p *= xv;
        float f = 1.0f;
        for (int q = 2; q <= n; ++q) f *= (float)q;
        cohr[m][n] = expf(-0.5f*xv*xv) * p / sqrtf(f);
    }
    __syncthreads();
    for (int idx = t; idx < D3; idx += 256) {
        int i2 = idx % 14, i1 = (idx/14) % 14, i0 = idx / 196;
        ps[idx] = make_float2(cohr[0][i0]*cohr[1][i1]*cohr[2][i2], 0.f);
    }
    __syncthreads();

    for (int l = 0; l < 2; ++l) {
        int gi = c*2 + l;
        const float2* bsb = g_gp + gi*6*GSTRIDE;
        ABS0(bsb + 0*GSTRIDE)
        ABS1(bsb + 1*GSTRIDE)
        ABS0(bsb + 2*GSTRIDE)
        apply_single<0>(g_gsr + (gi*3+0)*D2, ps, t);
        apply_single<1>(g_gsr + (gi*3+1)*D2, ps, t);
        apply_single<2>(g_gsr + (gi*3+2)*D2, ps, t);
        ABS0(bsb + 3*GSTRIDE)
        ABS1(bsb + 4*GSTRIDE)
        ABS0(bsb + 5*GSTRIDE)
        apply_single<0>(g_grdk + (gi*3+0)*D2, ps, t);
        apply_single<1>(g_grdk + (gi*3+1)*D2, ps, t);
        apply_single<2>(g_grdk + (gi*3+2)*D2, ps, t);
    }

    // <X_m> = 2 * sum sqrt(i_m+1) Re(conj(psi_i) psi_{i+e_m})
    float p0 = 0.f, p1 = 0.f, p2 = 0.f;
    for (int idx = t; idx < D3; idx += 256) {
        int i2 = idx % 14, i1 = (idx/14) % 14, i0 = idx / 196;
        float2 v = ps[idx];
        if (i0 < 13) { float2 w = ps[idx + 196]; p0 += sqrtf((float)(i0+1)) * (v.x*w.x + v.y*w.y); }
        if (i1 < 13) { float2 w = ps[idx + 14];  p1 += sqrtf((float)(i1+1)) * (v.x*w.x + v.y*w.y); }
        if (i2 < 13) { float2 w = ps[idx + 1];   p2 += sqrtf((float)(i2+1)) * (v.x*w.x + v.y*w.y); }
    }
    #pragma unroll
    for (int off = 32; off > 0; off >>= 1) {
        p0 += __shfl_down(p0, off, 64);
        p1 += __shfl_down(p1, off, 64);
        p2 += __shfl_down(p2, off, 64);
    }
    int lane = t & 63, w = t >> 6;
    if (lane == 0) { red[w*3+0] = p0; red[w*3+1] = p1; red[w*3+2] = p2; }
    __syncthreads();
    if (t == 0) {
        float o0 = 0.f, o1 = 0.f, o2 = 0.f;
        for (int q = 0; q < 4; ++q) { o0 += red[q*3]; o1 += red[q*3+1]; o2 += red[q*3+2]; }
        out[base6 + 0] = 2.0f * o0;
        out[base6 + 1] = 2.0f * o1;
        out[base6 + 2] = 2.0f * o2;
    }
}

extern "C" void kernel_launch(void* const* d_in, const int* in_sizes, int n_in,
                              void* d_out, int out_size, void* d_ws, size_t ws_size,
                              hipStream_t stream) {
    (void)d_ws; (void)ws_size;
    P12 P;
    for (int i = 0; i < 12; ++i) P.p[i] = (i < n_in) ? d_in[i] : nullptr;
    float* out = (float*)d_out;

    int ix = 0; long best = -1;
    for (int i = 0; i < 12 && i < n_in; ++i)
        if ((long)in_sizes[i] > best) { best = in_sizes[i]; ix = i; }
    int B = out_size / 6; if (B < 1) B = 1;

    build_all<<<672, 256, 0, stream>>>(P, ix);
    qcircuit<<<2*B, 256, 0, stream>>>(P, out);
}

// Round 19
// 437.509 us; speedup vs baseline: 1.7021x; 1.1142x over previous
//
#include <hip/hip_runtime.h>
#include <hip/hip_bf16.h>

typedef __hip_bfloat16 bf16;

#define CUT 14
#define D2 196
#define D3 2744
#define GSTRIDE 3584   // 14 ci * 256 threads per gate slab

#define SX 0
#define STH1 1
#define SPH1 2
#define SVPH1 3
#define SR 4
#define SPHR 5
#define STH2 6
#define SPH2 7
#define SVPH2 8
#define SA 9
#define SPHA 10
#define SK 11

// Packed thread->(n,a) map: every photon-number block fits inside ONE wave,
// so BS applies are wave-internal (no write barrier needed). [R15-verified
// tables — R18's failure was an accidental corruption of these constants]
__constant__ unsigned char c_PN[256] = {
13,13,13,13,13,13,13,13,13,13,13,13,13,13,
12,12,12,12,12,12,12,12,12,12,12,12,12,
14,14,14,14,14,14,14,14,14,14,14,14,14,
11,11,11,11,11,11,11,11,11,11,11,11,
15,15,15,15,15,15,15,15,15,15,15,15,
10,10,10,10,10,10,10,10,10,10,10,
16,16,16,16,16,16,16,16,16,16,16,
9,9,9,9,9,9,9,9,9,9,
17,17,17,17,17,17,17,17,17,17,
8,8,8,8,8,8,8,8,8,
18,18,18,18,18,18,18,18,18,
3,3,3,3,
7,7,7,7,7,7,7,7,
19,19,19,19,19,19,19,19,
6,6,6,6,6,6,6,
20,20,20,20,20,20,20,
5,5,5,5,5,5,
21,21,21,21,21,21,
4,4,4,4,4,
22,22,22,22,22,
23,23,23,23,
2,2,2,
24,24,24,
1,1,
25,25,
0,
26,
255,255,255,255,255,255,255,255,255,255,255,255,255,255,255,
255,255,255,255,255,255,255,255,255,255,255,255,255,255,255,
255,255,255,255,255,255,255,255,255,255,255,255,255,255,255,
255,255,255,255,255,255,255,255,255,255,255,255,255,255,255};
__constant__ unsigned char c_PA[256] = {
0,1,2,3,4,5,6,7,8,9,10,11,12,13,
0,1,2,3,4,5,6,7,8,9,10,11,12,
1,2,3,4,5,6,7,8,9,10,11,12,13,
0,1,2,3,4,5,6,7,8,9,10,11,
2,3,4,5,6,7,8,9,10,11,12,13,
0,1,2,3,4,5,6,7,8,9,10,
3,4,5,6,7,8,9,10,11,12,13,
0,1,2,3,4,5,6,7,8,9,
4,5,6,7,8,9,10,11,12,13,
0,1,2,3,4,5,6,7,8,
5,6,7,8,9,10,11,12,13,
0,1,2,3,
0,1,2,3,4,5,6,7,
6,7,8,9,10,11,12,13,
0,1,2,3,4,5,6,
7,8,9,10,11,12,13,
0,1,2,3,4,5,
8,9,10,11,12,13,
0,1,2,3,4,
9,10,11,12,13,
10,11,12,13,
0,1,2,
11,12,13,
0,1,
12,13,
0,
13,
0,0,0,0,0,0,0,0,0,0,0,0,0,0,0,
0,0,0,0,0,0,0,0,0,0,0,0,0,0,0,
0,0,0,0,0,0,0,0,0,0,0,0,0,0,0,
0,0,0,0,0,0,0,0,0,0,0,0,0,0,0};
// n -> packed start thread index
__constant__ short c_PSTART[27] = {194,190,184,124,170,158,144,128,106,86,64,40,14,0,
                                   27,52,75,96,115,136,151,164,175,180,187,192,195};

struct P12 { const void* p[12]; };

__device__ float2 g_gp[24 * GSTRIDE];   // BS gates, packed layout [gate][ci][t]
__device__ float2 g_gsr[12 * D2];
__device__ float2 g_grdk[12 * D2];
__device__ int    g_flag;
__device__ int    g_map[12];

__device__ __forceinline__ float2 cfma2(float2 acc, float2 a, float2 b) {
    acc.x = fmaf(a.x, b.x, fmaf(-a.y, b.y, acc.x));
    acc.y = fmaf(a.x, b.y, fmaf(a.y, b.x, acc.y));
    return acc;
}
__device__ __forceinline__ float2 cmul2(float2 a, float2 b) {
    return make_float2(a.x*b.x - a.y*b.y, a.x*b.y + a.y*b.x);
}
__device__ __forceinline__ float load_raw(const void* p, int i, int f32) {
    return f32 ? ((const float*)p)[i]
               : __bfloat162float(((const bf16*)p)[i]);
}

// Per-block layout/dtype detection (R5-proven: dict order, fp32, r/a at {4,9}).
__device__ void detect_layout(const P12& P, int ix, int* sh)
{
    int t = threadIdx.x;
    if (t < 13) sh[13 + t] = 0;
    __syncthreads();
    const unsigned int* u = (const unsigned int*)P.p[ix];
    if (t < 256) {
        if (u[t] & 0x8000u) atomicOr(&sh[25], 1);
    }
    __syncthreads();
    int f = sh[25] != 0 ? 1 : 0;
    if (t < 144) {
        int p = t / 12, j = t - (t/12)*12;
        if (p != ix) {
            float v = fabsf(load_raw(P.p[p], j, f));
            atomicMax(&sh[13 + p], __float_as_int(v));
        }
    }
    __syncthreads();
    if (t == 0) {
        int mask = 0;
        for (int i = 0; i < 12; ++i) {
            if (i == ix) continue;
            if (__int_as_float(sh[13 + i]) < 0.2f) mask |= (1 << i);
        }
        const int dict_map[12]  = {0,1,2,3,4,5,6,7,8,9,10,11};
        const int alpha_map[12] = {11,7,2,9,6,5,8,3,10,0,4,1};
        const int* m = (ix == 11 && mask == ((1<<0)|(1<<6))) ? alpha_map : dict_map;
        for (int i = 0; i < 12; ++i) sh[i] = m[i];
        sh[12] = f;
    }
    __syncthreads();
}

// expm light: scale 2^-10, 10 Taylor terms, 10 squarings (R15-proven accurate).
__device__ void expm_lds(float2* B, float2* TERM, float2* OUT, float2* TMP, int s, int t)
{
    const int s2 = s * s;
    if (t < s2) { B[t].x *= (1.0f/1024.0f); B[t].y *= (1.0f/1024.0f); }
    __syncthreads();
    if (t < s2) {
        float2 id = make_float2((t % (s + 1) == 0) ? 1.0f : 0.0f, 0.0f);
        TERM[t] = id; OUT[t] = id;
    }
    __syncthreads();
    for (int kk = 1; kk <= 10; ++kk) {
        if (t < s2) {
            int i = t / s, j = t - i * s;
            float2 acc = make_float2(0.f, 0.f);
            for (int k = 0; k < s; ++k) acc = cfma2(acc, TERM[i*s+k], B[k*s+j]);
            float inv = 1.0f / (float)kk;
            TMP[t] = make_float2(acc.x*inv, acc.y*inv);
        }
        __syncthreads();
        if (t < s2) { TERM[t] = TMP[t]; OUT[t].x += TMP[t].x; OUT[t].y += TMP[t].y; }
        __syncthreads();
    }
    for (int q = 0; q < 10; ++q) {
        if (t < s2) {
            int i = t / s, j = t - i * s;
            float2 acc = make_float2(0.f, 0.f);
            for (int k = 0; k < s; ++k) acc = cfma2(acc, OUT[i*s+k], OUT[k*s+j]);
            TMP[t] = acc;
        }
        __syncthreads();
        if (t < s2) OUT[t] = TMP[t];
        __syncthreads();
    }
}

// Unified builder: blocks 0..647 = BS gates (gate,n); 648..671 = singles.
__global__ __launch_bounds__(256)
void build_all(P12 P, int ix)
{
    __shared__ float2 B[D2], TERM[D2], OUT[D2], TMP[D2];
    __shared__ int sh[26];
    int t = threadIdx.x;
    detect_layout(P, ix, sh);
    const int f32 = sh[12];
    if (blockIdx.x == 0 && t == 0) {
        for (int i = 0; i < 12; ++i) g_map[i] = sh[i];
        g_flag = f32;
    }
    #define LS(slot, i) load_raw(P.p[sh[(slot)]], (i), f32)

    if (blockIdx.x < 648) {
        int gate = blockIdx.x / 27;
        int n    = blockIdx.x % 27;
        int cc   = gate / 12;
        int l    = (gate / 6) % 2;
        int slot = gate % 6;
        int p    = slot % 3;
        int pidx = (cc*2 + l)*3 + p;
        float th = LS(slot < 3 ? STH1 : STH2, pidx);
        float ph = LS(slot < 3 ? SPH1 : SPH2, pidx);
        float cph, sph; sincosf(ph, &sph, &cph);
        int cmin = max(0, n - 13);
        int cmax = min(13, n);
        int s = cmax - cmin + 1;
        if (t < s*s) {
            int i = t / s, j = t - (t/s)*s;
            float2 h = make_float2(0.f, 0.f);
            int cj = cmin + j;
            if (i == j + 1) {
                float sq = th * sqrtf((float)((cj+1)*(n-cj)));
                h = make_float2(sq*cph, sq*sph);
            } else if (i == j - 1) {
                float sq = th * sqrtf((float)(cj*(n-cj+1)));
                h = make_float2(-sq*cph, sq*sph);
            }
            B[t] = h;
        }
        __syncthreads();
        expm_lds(B, TERM, OUT, TMP, s, t);
        if (t < s*14) {
            int ii = t / 14, ci = t - (t/14)*14;
            float2 v = (ci < s) ? OUT[ii*s + ci] : make_float2(0.f, 0.f);
            g_gp[gate*GSTRIDE + ci*256 + (c_PSTART[n] + ii)] = v;
        }
    } else {
        int q = blockIdx.x - 648;        // 0..23
        int pidx = q >> 1;
        if ((q & 1) == 0) {
            // gsr = SQ(r,phi_r) @ diag(e^{i varphi1 j})
            float rv = LS(SR, pidx);
            float pv = LS(SPHR, pidx);
            float cp, sp; sincosf(pv, &sp, &cp);
            if (t < D2) {
                int i = t / 14, j = t - (t/14)*14;
                float2 h = make_float2(0.f, 0.f);
                if (j == i + 2) {
                    float s = 0.5f * rv * sqrtf((float)((i+1)*(i+2)));
                    h = make_float2(s*cp, -s*sp);
                } else if (i == j + 2) {
                    float s = 0.5f * rv * sqrtf((float)((j+1)*(j+2)));
                    h = make_float2(-s*cp, -s*sp);
                }
                B[t] = h;
            }
            __syncthreads();
            expm_lds(B, TERM, OUT, TMP, 14, t);
            float v1 = LS(SVPH1, pidx);
            if (t < D2) {
                int j = t - (t/14)*14;
                float cs, sn; sincosf(v1 * (float)j, &sn, &cs);
                g_gsr[pidx*D2 + t] = cmul2(OUT[t], make_float2(cs, sn));
            }
        } else {
            // grdk = diag(e^{i k i^2}) @ D(a,phi_a) @ diag(e^{i varphi2 j})
            float av = LS(SA, pidx);
            float pav = LS(SPHA, pidx);
            float ca, sa; sincosf(pav, &sa, &ca);
            if (t < D2) {
                int i = t / 14, j = t - (t/14)*14;
                float2 h = make_float2(0.f, 0.f);
                if (i == j + 1) {
                    float s = av * sqrtf((float)(j+1));
                    h = make_float2(s*ca, s*sa);
                } else if (j == i + 1) {
                    float s = av * sqrtf((float)(i+1));
                    h = make_float2(-s*ca, s*sa);
                }
                B[t] = h;
            }
            __syncthreads();
            expm_lds(B, TERM, OUT, TMP, 14, t);
            float v2 = LS(SVPH2, pidx);
            float kv = LS(SK, pidx);
            if (t < D2) {
                int i = t / 14, j = t - (t/14)*14;
                float ang = kv * (float)(i*i) + v2 * (float)j;
                float cs, sn; sincosf(ang, &sn, &cs);
                g_grdk[pidx*D2 + t] = cmul2(OUT[t], make_float2(cs, sn));
            }
        }
    }
    #undef LS
}

// ---- main circuit kernel: single psi buffer; BS applies wave-internal ----
// PAIR=0: spectator i2 contiguous -> b128 (float4) reads/writes (halves LDS
// issue count, the measured bottleneck). PAIR=1: scalar b64 path.
// NOTE: no min-waves launch bound — R17's (256,7) made the compiler spill
// u[]/acc[] to scratch (WRITE_SIZE 80KB -> 493MB, VGPR 36): catastrophic.

template<int PAIR>
__device__ void apply_bs(const float2* __restrict__ G, float2* ps, int t,
                         int aP, int nP, int sP, int cminP)
{
    if (nP != 255) {
        float2 u[14];
        #pragma unroll
        for (int ci = 0; ci < 14; ++ci) u[ci] = G[ci*256 + t];
        float2 acc[14];
        #pragma unroll
        for (int k = 0; k < 14; ++k) acc[k] = make_float2(0.f, 0.f);
        if (PAIR == 0) {
            const float4* ps4 = (const float4*)ps;
            #pragma unroll
            for (int ci = 0; ci < 14; ++ci) {
                if (ci < sP) {
                    int c = cminP + ci;
                    const float4* sp4 = ps4 + (c*14 + (nP - c))*7;
                    #pragma unroll
                    for (int q = 0; q < 7; ++q) {
                        float4 r = sp4[q];
                        acc[2*q]   = cfma2(acc[2*q],   u[ci], make_float2(r.x, r.y));
                        acc[2*q+1] = cfma2(acc[2*q+1], u[ci], make_float2(r.z, r.w));
                    }
                }
            }
            float4* dp4 = (float4*)ps + (aP*14 + (nP - aP))*7;
            #pragma unroll
            for (int q = 0; q < 7; ++q)
                dp4[q] = make_float4(acc[2*q].x, acc[2*q].y, acc[2*q+1].x, acc[2*q+1].y);
        } else {
            #pragma unroll
            for (int ci = 0; ci < 14; ++ci) {
                if (ci < sP) {
                    int c = cminP + ci;
                    const float2* sp = ps + c*14 + (nP - c);
                    #pragma unroll
                    for (int k = 0; k < 14; ++k)
                        acc[k] = cfma2(acc[k], u[ci], sp[k*196]);
                }
            }
            float2* dp = ps + aP*14 + (nP - aP);
            #pragma unroll
            for (int k = 0; k < 14; ++k) dp[k*196] = acc[k];
        }
    }
    __syncthreads();
}

// Singles: thread owns its fiber exclusively -> in-place. MODE 2 contiguous
// -> b128 vectorized.
template<int MODE>
__device__ void apply_single(const float2* __restrict__ U, float2* ps, int t)
{
    if (t < D2) {
        float2 fib[14];
        if (MODE == 2) {
            const float4* bp = (const float4*)ps + t*7;
            #pragma unroll
            for (int q = 0; q < 7; ++q) {
                float4 r = bp[q];
                fib[2*q]   = make_float2(r.x, r.y);
                fib[2*q+1] = make_float2(r.z, r.w);
            }
            float2 res[14];
            #pragma unroll
            for (int i = 0; i < 14; ++i) {
                float2 acc = make_float2(0.f, 0.f);
                #pragma unroll
                for (int j = 0; j < 14; ++j) acc = cfma2(acc, U[i*14 + j], fib[j]);
                res[i] = acc;
            }
            float4* dp = (float4*)ps + t*7;
            #pragma unroll
            for (int q = 0; q < 7; ++q)
                dp[q] = make_float4(res[2*q].x, res[2*q].y, res[2*q+1].x, res[2*q+1].y);
        } else {
            int base, stride;
            if (MODE == 0) { base = t; stride = 196; }
            else           { base = (t/14)*196 + (t % 14); stride = 14; }
            #pragma unroll
            for (int j = 0; j < 14; ++j) fib[j] = ps[base + j*stride];
            #pragma unroll
            for (int i = 0; i < 14; ++i) {
                float2 acc = make_float2(0.f, 0.f);
                #pragma unroll
                for (int j = 0; j < 14; ++j) acc = cfma2(acc, U[i*14 + j], fib[j]);
                ps[base + i*stride] = acc;
            }
        }
    }
    __syncthreads();
}

#define ABS0(G) apply_bs<0>(G, ps, t, aP, nP, sP, cminP);
#define ABS1(G) apply_bs<1>(G, ps, t, aP, nP, sP, cminP);

__global__ __launch_bounds__(256)
void qcircuit(P12 P, float* __restrict__ out)
{
    __shared__ __align__(16) float2 ps[D3];
    __shared__ float cohr[3][14];
    __shared__ float red[12];
    int t = threadIdx.x;
    int b = blockIdx.x >> 1;
    int c = blockIdx.x & 1;
    int base6 = b*6 + c*3;
    int f32 = g_flag;

    int nP = (int)c_PN[t];
    int aP = (int)c_PA[t];
    int cminP = max(0, nP - 13);
    int sP = min(13, nP) - cminP + 1;

    if (t < 42) {
        int m = t / 14, n = t - (t/14)*14;
        float xv = load_raw(P.p[g_map[SX]], base6 + m, f32);
        float p = 1.0f;
        for (int q = 0; q < n; ++q) p *= xv;
        float f = 1.0f;
        for (int q = 2; q <= n; ++q) f *= (float)q;
        cohr[m][n] = expf(-0.5f*xv*xv) * p / sqrtf(f);
    }
    __syncthreads();
    for (int idx = t; idx < D3; idx += 256) {
        int i2 = idx % 14, i1 = (idx/14) % 14, i0 = idx / 196;
        ps[idx] = make_float2(cohr[0][i0]*cohr[1][i1]*cohr[2][i2], 0.f);
    }
    __syncthreads();

    for (int l = 0; l < 2; ++l) {
        int gi = c*2 + l;
        const float2* bsb = g_gp + gi*6*GSTRIDE;
        ABS0(bsb + 0*GSTRIDE)
        ABS1(bsb + 1*GSTRIDE)
        ABS0(bsb + 2*GSTRIDE)
        apply_single<0>(g_gsr + (gi*3+0)*D2, ps, t);
        apply_single<1>(g_gsr + (gi*3+1)*D2, ps, t);
        apply_single<2>(g_gsr + (gi*3+2)*D2, ps, t);
        ABS0(bsb + 3*GSTRIDE)
        ABS1(bsb + 4*GSTRIDE)
        ABS0(bsb + 5*GSTRIDE)
        apply_single<0>(g_grdk + (gi*3+0)*D2, ps, t);
        apply_single<1>(g_grdk + (gi*3+1)*D2, ps, t);
        apply_single<2>(g_grdk + (gi*3+2)*D2, ps, t);
    }

    // <X_m> = 2 * sum sqrt(i_m+1) Re(conj(psi_i) psi_{i+e_m})
    float p0 = 0.f, p1 = 0.f, p2 = 0.f;
    for (int idx = t; idx < D3; idx += 256) {
        int i2 = idx % 14, i1 = (idx/14) % 14, i0 = idx / 196;
        float2 v = ps[idx];
        if (i0 < 13) { float2 w = ps[idx + 196]; p0 += sqrtf((float)(i0+1)) * (v.x*w.x + v.y*w.y); }
        if (i1 < 13) { float2 w = ps[idx + 14];  p1 += sqrtf((float)(i1+1)) * (v.x*w.x + v.y*w.y); }
        if (i2 < 13) { float2 w = ps[idx + 1];   p2 += sqrtf((float)(i2+1)) * (v.x*w.x + v.y*w.y); }
    }
    #pragma unroll
    for (int off = 32; off > 0; off >>= 1) {
        p0 += __shfl_down(p0, off, 64);
        p1 += __shfl_down(p1, off, 64);
        p2 += __shfl_down(p2, off, 64);
    }
    int lane = t & 63, w = t >> 6;
    if (lane == 0) { red[w*3+0] = p0; red[w*3+1] = p1; red[w*3+2] = p2; }
    __syncthreads();
    if (t == 0) {
        float o0 = 0.f, o1 = 0.f, o2 = 0.f;
        for (int q = 0; q < 4; ++q) { o0 += red[q*3]; o1 += red[q*3+1]; o2 += red[q*3+2]; }
        out[base6 + 0] = 2.0f * o0;
        out[base6 + 1] = 2.0f * o1;
        out[base6 + 2] = 2.0f * o2;
    }
}

extern "C" void kernel_launch(void* const* d_in, const int* in_sizes, int n_in,
                              void* d_out, int out_size, void* d_ws, size_t ws_size,
                              hipStream_t stream) {
    (void)d_ws; (void)ws_size;
    P12 P;
    for (int i = 0; i < 12; ++i) P.p[i] = (i < n_in) ? d_in[i] : nullptr;
    float* out = (float*)d_out;

    int ix = 0; long best = -1;
    for (int i = 0; i < 12 && i < n_in; ++i)
        if ((long)in_sizes[i] > best) { best = in_sizes[i]; ix = i; }
    int B = out_size / 6; if (B < 1) B = 1;

    build_all<<<672, 256, 0, stream>>>(P, ix);
    qcircuit<<<2*B, 256, 0, stream>>>(P, out);
}